// Round 2
// baseline (102.809 us; speedup 1.0000x reference)
//
#include <hip/hip_runtime.h>
#include <math.h>

#define NB 32
#define NI 1024
#define NJ 2048
#define NC 1024
#define K2 2048   // 2*NI

// Merge two sorted-descending 16-lists -> top-16 sorted descending (in v).
__device__ __forceinline__ void merge16(float* __restrict__ v,
                                        const float* __restrict__ w) {
    float m[16];
#pragma unroll
    for (int i = 0; i < 16; ++i) m[i] = fmaxf(v[i], w[15 - i]);  // bitonic split
#pragma unroll
    for (int st = 8; st >= 1; st >>= 1)                          // bitonic cleanup
#pragma unroll
        for (int i = 0; i < 16; ++i)
            if ((i & st) == 0) {
                float x = m[i], y = m[i + st];
                m[i] = fmaxf(x, y);
                m[i + st] = fminf(x, y);
            }
#pragma unroll
    for (int i = 0; i < 16; ++i) v[i] = m[i];
}

// ---------------------------------------------------------------------------
// Kernel A: per-batch prep (one block per batch).
// sim[b,i,j] = r_n[b,i]*h_n[b,j] is rank-1, so top/bottom-16 over j depends
// only on sign(r_n):  pos = rn>0 ? rn*Hpos : rn*Hneg ; neg = -(rn>0?Hneg:Hpos)*rn
// with Hpos/Hneg = mean of top/bottom 16 of h_n.
// Single merge-tree pass computes BOTH top-16 and bottom-16 (halves barriers).
// ---------------------------------------------------------------------------
__global__ __launch_bounds__(256)
void prep_kernel(const float* __restrict__ f_rad,
                 const float* __restrict__ f_histo,
                 const unsigned char* __restrict__ rad_mask,
                 const unsigned char* __restrict__ histo_mask,
                 const float* __restrict__ bias,
                 const float* __restrict__ token,
                 float* __restrict__ F,
                 float* __restrict__ out)
{
    __shared__ float listsP[256][16];   // 16 KB
    __shared__ float listsN[256][16];   // 16 KB
    __shared__ float red[4];

    const int b = blockIdx.x;
    const int t = threadIdx.x;
    const int wave = t >> 6, lane = t & 63;

    // ---- h row: load to registers + sum of squares (shfl butterfly) ----
    float hv[8];
    float ss = 0.f;
#pragma unroll
    for (int i = 0; i < 8; ++i) {
        hv[i] = f_histo[b * NJ + t + i * 256];
        ss += hv[i] * hv[i];
    }
#pragma unroll
    for (int off = 1; off < 64; off <<= 1) ss += __shfl_xor(ss, off, 64);
    if (lane == 0) red[wave] = ss;

    // ---- per-thread sorted-desc lists: top candidates & negated (bottom) ----
    float vp[16], vn[16];
#pragma unroll
    for (int i = 0; i < 8; ++i) { vp[i] = hv[i]; vn[i] = -hv[i]; }
#pragma unroll
    for (int i = 8; i < 16; ++i) { vp[i] = -INFINITY; vn[i] = -INFINITY; }
#pragma unroll
    for (int a = 0; a < 7; ++a)          // bubble network, compile-time idx
#pragma unroll
        for (int c = 0; c < 7 - a; ++c) {
            float x = vp[c], y = vp[c + 1];
            vp[c] = fmaxf(x, y); vp[c + 1] = fminf(x, y);
            x = vn[c]; y = vn[c + 1];
            vn[c] = fmaxf(x, y); vn[c + 1] = fminf(x, y);
        }

    __syncthreads();                     // red[] visible to all
    const float hnorm = fmaxf(sqrtf(red[0] + red[1] + red[2] + red[3]), 1e-12f);

#pragma unroll
    for (int i = 0; i < 16; ++i) { listsP[t][i] = vp[i]; listsN[t][i] = vn[i]; }
    __syncthreads();

    // ---- merge tree: 256 lists -> 1, both P and N per level ----
#pragma unroll
    for (int s = 128; s >= 1; s >>= 1) {
        if (t < s) {
            float wp[16], wn[16];
#pragma unroll
            for (int i = 0; i < 16; ++i) { wp[i] = listsP[t + s][i]; wn[i] = listsN[t + s][i]; }
            merge16(vp, wp);
            merge16(vn, wn);
#pragma unroll
            for (int i = 0; i < 16; ++i) { listsP[t][i] = vp[i]; listsN[t][i] = vn[i]; }
        }
        __syncthreads();
    }

    // all threads read the final lists and compute the scalars themselves
    float sumP = 0.f, sumN = 0.f;
#pragma unroll
    for (int i = 0; i < 16; ++i) { sumP += listsP[0][i]; sumN += listsN[0][i]; }
    const float Hpos = sumP / (16.f * hnorm);    // mean of top-16 of h_n
    const float Hneg = -sumN / (16.f * hnorm);   // mean of bottom-16 of h_n

    // ---- f_rad row: norm ----
    float rv[4];
    float ss2 = 0.f;
#pragma unroll
    for (int i = 0; i < 4; ++i) {
        rv[i] = f_rad[b * NI + t + i * 256];
        ss2 += rv[i] * rv[i];
    }
#pragma unroll
    for (int off = 1; off < 64; off <<= 1) ss2 += __shfl_xor(ss2, off, 64);
    __syncthreads();                     // everyone done reading red / lists
    if (lane == 0) red[wave] = ss2;
    __syncthreads();
    const float rnorm = fmaxf(sqrtf(red[0] + red[1] + red[2] + red[3]), 1e-12f);

    // ---- write F (the analytic feat = [pos_map ; neg_map]) ----
#pragma unroll
    for (int i = 0; i < 4; ++i) {
        float rn = rv[i] / rnorm;
        float p, q;
        if (rn > 0.f) { p = rn * Hpos;  q = -rn * Hneg; }
        else          { p = rn * Hneg;  q = -rn * Hpos; }
        F[b * K2 + t + i * 256]      = p;
        F[b * K2 + NI + t + i * 256] = q;
    }

    // ---- out init: bias + token*flag (gemm atomicAdds on top) ----
    const float flag = (rad_mask[b] != 0 && histo_mask[b] != 0) ? 0.f : 1.f;
#pragma unroll
    for (int i = 0; i < NC / 256; ++i) {
        int c = t + i * 256;
        out[b * NC + c] = bias[c] + token[c] * flag;
    }
}

// ---------------------------------------------------------------------------
// Kernel B: out[b,c] += sum_k F[b,k] * W[c,k]
// grid (128, 2): c-tile of 8 (2 c per wave), k-half of 1024.
// No LDS: F is 256 KB, L2-resident — coalesced float4 global reads.
// Lanes parallel over k; c-folded butterfly reduce; atomicAdd into out.
// ---------------------------------------------------------------------------
__global__ __launch_bounds__(256)
void gemm_kernel(const float4* __restrict__ F4,
                 const float* __restrict__ W,
                 float* __restrict__ out)
{
    const int t = threadIdx.x;
    const int wave = t >> 6, lane = t & 63;
    const int c0 = blockIdx.x * 8 + wave * 2;
    const int kb4 = blockIdx.y * 256;            // float4 offset of k-half

    float acc0[32], acc1[32];
#pragma unroll
    for (int b = 0; b < 32; ++b) { acc0[b] = 0.f; acc1[b] = 0.f; }

    const float4* Wr0 = reinterpret_cast<const float4*>(W + (size_t)c0 * K2) + kb4;
    const float4* Wr1 = reinterpret_cast<const float4*>(W + (size_t)(c0 + 1) * K2) + kb4;

#pragma unroll
    for (int r = 0; r < 4; ++r) {
        const int kk4 = r * 64 + lane;           // 0..255 within the half
        float4 w0 = Wr0[kk4];
        float4 w1 = Wr1[kk4];
#pragma unroll
        for (int b = 0; b < 32; ++b) {
            float4 fv = F4[b * 512 + kb4 + kk4];
            acc0[b] = fmaf(fv.x, w0.x, acc0[b]);
            acc0[b] = fmaf(fv.y, w0.y, acc0[b]);
            acc0[b] = fmaf(fv.z, w0.z, acc0[b]);
            acc0[b] = fmaf(fv.w, w0.w, acc0[b]);
            acc1[b] = fmaf(fv.x, w1.x, acc1[b]);
            acc1[b] = fmaf(fv.y, w1.y, acc1[b]);
            acc1[b] = fmaf(fv.z, w1.z, acc1[b]);
            acc1[b] = fmaf(fv.w, w1.w, acc1[b]);
        }
    }

    // c-folded reduce: offset-1 step folds (c0,c0+1) by lane parity,
    // remaining butterfly sums all lanes of the same parity.
    float z[32];
#pragma unroll
    for (int b = 0; b < 32; ++b) {
        float a0 = acc0[b] + __shfl_xor(acc0[b], 1, 64);
        float a1 = acc1[b] + __shfl_xor(acc1[b], 1, 64);
        z[b] = (lane & 1) ? a1 : a0;
#pragma unroll
        for (int off = 2; off < 64; off <<= 1)
            z[b] += __shfl_xor(z[b], off, 64);
    }
    // lane l holds the full k-partial sum for c = c0+(l&1); pick b = l>>1
    const int bsel = lane >> 1;
    float myval = 0.f;
#pragma unroll
    for (int b = 0; b < 32; ++b)
        if (bsel == b) myval = z[b];

    atomicAdd(&out[bsel * NC + c0 + (lane & 1)], myval);
}

extern "C" void kernel_launch(void* const* d_in, const int* in_sizes, int n_in,
                              void* d_out, int out_size, void* d_ws, size_t ws_size,
                              hipStream_t stream) {
    const float* f_rad       = (const float*)d_in[0];
    const float* f_histo     = (const float*)d_in[1];
    const unsigned char* rm  = (const unsigned char*)d_in[2];
    const unsigned char* hm  = (const unsigned char*)d_in[3];
    const float* W           = (const float*)d_in[4];
    const float* bias        = (const float*)d_in[5];
    const float* token       = (const float*)d_in[6];
    float* out = (float*)d_out;
    float* F   = (float*)d_ws;   // 32*2048 floats = 256 KB

    prep_kernel<<<NB, 256, 0, stream>>>(f_rad, f_histo, rm, hm, bias, token, F, out);
    dim3 grid(128, 2);
    gemm_kernel<<<grid, 256, 0, stream>>>((const float4*)F, W, out);
}

// Round 3
// 90.743 us; speedup vs baseline: 1.1330x; 1.1330x over previous
//
#include <hip/hip_runtime.h>
#include <math.h>

#define NB 32
#define NI 1024
#define NJ 2048
#define NC 1024
#define K2 2048   // 2*NI

// Merge two sorted-descending 16-lists -> top-16 sorted descending (in v).
__device__ __forceinline__ void merge16(float* __restrict__ v,
                                        const float* __restrict__ w) {
    float m[16];
#pragma unroll
    for (int i = 0; i < 16; ++i) m[i] = fmaxf(v[i], w[15 - i]);  // bitonic split
#pragma unroll
    for (int st = 8; st >= 1; st >>= 1)                          // bitonic cleanup
#pragma unroll
        for (int i = 0; i < 16; ++i)
            if ((i & st) == 0) {
                float x = m[i], y = m[i + st];
                m[i] = fmaxf(x, y);
                m[i + st] = fminf(x, y);
            }
#pragma unroll
    for (int i = 0; i < 16; ++i) v[i] = m[i];
}

// ---------------------------------------------------------------------------
// Kernel A: per-batch prep (one block per batch). UNCHANGED from R2 (correct).
// sim[b,i,j] = r_n[b,i]*h_n[b,j] is rank-1, so top/bottom-16 over j depends
// only on sign(r_n):  pos = rn>0 ? rn*Hpos : rn*Hneg ; neg = -(rn>0?Hneg:Hpos)*rn
// with Hpos/Hneg = mean of top/bottom 16 of h_n.
// ---------------------------------------------------------------------------
__global__ __launch_bounds__(256)
void prep_kernel(const float* __restrict__ f_rad,
                 const float* __restrict__ f_histo,
                 const unsigned char* __restrict__ rad_mask,
                 const unsigned char* __restrict__ histo_mask,
                 const float* __restrict__ bias,
                 const float* __restrict__ token,
                 float* __restrict__ F,
                 float* __restrict__ out)
{
    __shared__ float listsP[256][16];   // 16 KB
    __shared__ float listsN[256][16];   // 16 KB
    __shared__ float red[4];

    const int b = blockIdx.x;
    const int t = threadIdx.x;
    const int wave = t >> 6, lane = t & 63;

    // ---- h row: load to registers + sum of squares (shfl butterfly) ----
    float hv[8];
    float ss = 0.f;
#pragma unroll
    for (int i = 0; i < 8; ++i) {
        hv[i] = f_histo[b * NJ + t + i * 256];
        ss += hv[i] * hv[i];
    }
#pragma unroll
    for (int off = 1; off < 64; off <<= 1) ss += __shfl_xor(ss, off, 64);
    if (lane == 0) red[wave] = ss;

    // ---- per-thread sorted-desc lists: top candidates & negated (bottom) ----
    float vp[16], vn[16];
#pragma unroll
    for (int i = 0; i < 8; ++i) { vp[i] = hv[i]; vn[i] = -hv[i]; }
#pragma unroll
    for (int i = 8; i < 16; ++i) { vp[i] = -INFINITY; vn[i] = -INFINITY; }
#pragma unroll
    for (int a = 0; a < 7; ++a)          // bubble network, compile-time idx
#pragma unroll
        for (int c = 0; c < 7 - a; ++c) {
            float x = vp[c], y = vp[c + 1];
            vp[c] = fmaxf(x, y); vp[c + 1] = fminf(x, y);
            x = vn[c]; y = vn[c + 1];
            vn[c] = fmaxf(x, y); vn[c + 1] = fminf(x, y);
        }

    __syncthreads();                     // red[] visible to all
    const float hnorm = fmaxf(sqrtf(red[0] + red[1] + red[2] + red[3]), 1e-12f);

#pragma unroll
    for (int i = 0; i < 16; ++i) { listsP[t][i] = vp[i]; listsN[t][i] = vn[i]; }
    __syncthreads();

    // ---- merge tree: 256 lists -> 1, both P and N per level ----
#pragma unroll
    for (int s = 128; s >= 1; s >>= 1) {
        if (t < s) {
            float wp[16], wn[16];
#pragma unroll
            for (int i = 0; i < 16; ++i) { wp[i] = listsP[t + s][i]; wn[i] = listsN[t + s][i]; }
            merge16(vp, wp);
            merge16(vn, wn);
#pragma unroll
            for (int i = 0; i < 16; ++i) { listsP[t][i] = vp[i]; listsN[t][i] = vn[i]; }
        }
        __syncthreads();
    }

    // all threads read the final lists and compute the scalars themselves
    float sumP = 0.f, sumN = 0.f;
#pragma unroll
    for (int i = 0; i < 16; ++i) { sumP += listsP[0][i]; sumN += listsN[0][i]; }
    const float Hpos = sumP / (16.f * hnorm);    // mean of top-16 of h_n
    const float Hneg = -sumN / (16.f * hnorm);   // mean of bottom-16 of h_n

    // ---- f_rad row: norm ----
    float rv[4];
    float ss2 = 0.f;
#pragma unroll
    for (int i = 0; i < 4; ++i) {
        rv[i] = f_rad[b * NI + t + i * 256];
        ss2 += rv[i] * rv[i];
    }
#pragma unroll
    for (int off = 1; off < 64; off <<= 1) ss2 += __shfl_xor(ss2, off, 64);
    __syncthreads();                     // everyone done reading red / lists
    if (lane == 0) red[wave] = ss2;
    __syncthreads();
    const float rnorm = fmaxf(sqrtf(red[0] + red[1] + red[2] + red[3]), 1e-12f);

    // ---- write F (the analytic feat = [pos_map ; neg_map]) ----
#pragma unroll
    for (int i = 0; i < 4; ++i) {
        float rn = rv[i] / rnorm;
        float p, q;
        if (rn > 0.f) { p = rn * Hpos;  q = -rn * Hneg; }
        else          { p = rn * Hneg;  q = -rn * Hpos; }
        F[b * K2 + t + i * 256]      = p;
        F[b * K2 + NI + t + i * 256] = q;
    }

    // ---- out init: bias + token*flag (gemm atomicAdds on top) ----
    const float flag = (rad_mask[b] != 0 && histo_mask[b] != 0) ? 0.f : 1.f;
#pragma unroll
    for (int i = 0; i < NC / 256; ++i) {
        int c = t + i * 256;
        out[b * NC + c] = bias[c] + token[c] * flag;
    }
}

// ---------------------------------------------------------------------------
// Kernel B: out[b,c] += sum_k F[b,k] * W[c,k]
// grid (128, 8): c-tile of 8 (2 c per wave), k-split of 256 floats.
// 1024 blocks = 4 blocks/CU (vs 1 in R2) -> 4 waves/SIMD latency hiding.
// Register-halving transpose reduce: 63 shfl vs 224.
// __launch_bounds__(256,4): cap VGPR at 128 to guarantee 4 waves/SIMD.
// ---------------------------------------------------------------------------
__global__ __launch_bounds__(256, 4)
void gemm_kernel(const float4* __restrict__ F4,
                 const float4* __restrict__ WF4,
                 float* __restrict__ out)
{
    const int t = threadIdx.x;
    const int wave = t >> 6, lane = t & 63;
    const int c0 = blockIdx.x * 8 + wave * 2;
    const int kk4 = blockIdx.y * 64 + lane;      // float4 index in [0,512)

    const float4 w0 = WF4[(size_t)c0 * 512 + kk4];
    const float4 w1 = WF4[(size_t)(c0 + 1) * 512 + kk4];

    float acc0[32], acc1[32];
#pragma unroll
    for (int b = 0; b < 32; ++b) { acc0[b] = 0.f; acc1[b] = 0.f; }

#pragma unroll
    for (int bb = 0; bb < 32; bb += 4) {
        float4 fv[4];
#pragma unroll
        for (int u = 0; u < 4; ++u) fv[u] = F4[(bb + u) * 512 + kk4];
#pragma unroll
        for (int u = 0; u < 4; ++u) {
            const int b = bb + u;
            acc0[b] = fmaf(fv[u].x, w0.x, acc0[b]);
            acc0[b] = fmaf(fv[u].y, w0.y, acc0[b]);
            acc0[b] = fmaf(fv[u].z, w0.z, acc0[b]);
            acc0[b] = fmaf(fv[u].w, w0.w, acc0[b]);
            acc1[b] = fmaf(fv[u].x, w1.x, acc1[b]);
            acc1[b] = fmaf(fv[u].y, w1.y, acc1[b]);
            acc1[b] = fmaf(fv[u].z, w1.z, acc1[b]);
            acc1[b] = fmaf(fv[u].w, w1.w, acc1[b]);
        }
    }

    // ---- c-fold (offset 1): z[b] = k-partial for c = c0+(lane&1) ----
    const bool odd = lane & 1;
    float z[32];
#pragma unroll
    for (int b = 0; b < 32; ++b) {
        float send = odd ? acc0[b] : acc1[b];    // value the partner keeps
        float recv = __shfl_xor(send, 1, 64);
        z[b] = (odd ? acc1[b] : acc0[b]) + recv;
    }

    // ---- register-halving reduce over 32 lane-pairs ----
    // invariant after step j: z[m] = partial for b = (m<<(j+1)) | (p mod 2^(j+1)),
    // summed over lane-pairs agreeing with p in low j+1 bits (p = lane>>1).
#pragma unroll
    for (int j = 0; j < 5; ++j) {
        const int o = 2 << j;
        const bool hi = (lane & o) != 0;         // bit_j(p)
        const int n = 32 >> (j + 1);
#pragma unroll
        for (int m = 0; m < n; ++m) {
            float send = hi ? z[2 * m] : z[2 * m + 1];   // entry partner keeps
            float recv = __shfl_xor(send, o, 64);
            z[m] = (hi ? z[2 * m + 1] : z[2 * m]) + recv;
        }
    }

    // lane l holds full k-partial for b = l>>1, c = c0 + (l&1)
    atomicAdd(&out[(lane >> 1) * NC + c0 + (lane & 1)], z[0]);
}

extern "C" void kernel_launch(void* const* d_in, const int* in_sizes, int n_in,
                              void* d_out, int out_size, void* d_ws, size_t ws_size,
                              hipStream_t stream) {
    const float* f_rad       = (const float*)d_in[0];
    const float* f_histo     = (const float*)d_in[1];
    const unsigned char* rm  = (const unsigned char*)d_in[2];
    const unsigned char* hm  = (const unsigned char*)d_in[3];
    const float* W           = (const float*)d_in[4];
    const float* bias        = (const float*)d_in[5];
    const float* token       = (const float*)d_in[6];
    float* out = (float*)d_out;
    float* F   = (float*)d_ws;   // 32*2048 floats = 256 KB

    prep_kernel<<<NB, 256, 0, stream>>>(f_rad, f_histo, rm, hm, bias, token, F, out);
    dim3 grid(128, 8);
    gemm_kernel<<<grid, 256, 0, stream>>>((const float4*)F, (const float4*)W, out);
}

// Round 4
// 88.847 us; speedup vs baseline: 1.1571x; 1.0213x over previous
//
#include <hip/hip_runtime.h>
#include <math.h>

#define NB 32
#define NI 1024
#define NJ 2048
#define NC 1024
#define K2 2048   // 2*NI

// Merge two sorted-descending 16-lists -> top-16 of union, sorted desc (in v).
__device__ __forceinline__ void merge16(float* __restrict__ v,
                                        const float* __restrict__ w) {
    float m[16];
#pragma unroll
    for (int i = 0; i < 16; ++i) m[i] = fmaxf(v[i], w[15 - i]);  // bitonic split
#pragma unroll
    for (int st = 8; st >= 1; st >>= 1)                          // bitonic cleanup
#pragma unroll
        for (int i = 0; i < 16; ++i)
            if ((i & st) == 0) {
                float x = m[i], y = m[i + st];
                m[i] = fmaxf(x, y);
                m[i + st] = fminf(x, y);
            }
#pragma unroll
    for (int i = 0; i < 16; ++i) v[i] = m[i];
}

// Full merge of two sorted-descending 8-lists -> sorted-16 desc in m.
__device__ __forceinline__ void merge8to16(const float* __restrict__ a,
                                           const float* __restrict__ w,
                                           float* __restrict__ m) {
#pragma unroll
    for (int i = 0; i < 8; ++i) m[i] = a[i];
#pragma unroll
    for (int i = 0; i < 8; ++i) m[8 + i] = w[7 - i];   // desc ++ asc = bitonic
#pragma unroll
    for (int st = 8; st >= 1; st >>= 1)
#pragma unroll
        for (int i = 0; i < 16; ++i)
            if ((i & st) == 0) {
                float x = m[i], y = m[i + st];
                m[i] = fmaxf(x, y);
                m[i + st] = fminf(x, y);
            }
}

__device__ __forceinline__ void sort8_desc(float* __restrict__ v) {
#pragma unroll
    for (int a = 0; a < 7; ++a)
#pragma unroll
        for (int c = 0; c < 7 - a; ++c) {
            float x = v[c], y = v[c + 1];
            v[c] = fmaxf(x, y);
            v[c + 1] = fminf(x, y);
        }
}

// ---------------------------------------------------------------------------
// Kernel A: per-batch prep (one block per batch).
// sim[b,i,j] = r_n[b,i]*h_n[b,j] is rank-1, so top/bottom-16 over j depends
// only on sign(r_n):  pos = rn>0 ? rn*Hpos : rn*Hneg ; neg = -(rn>0?Hneg:Hpos)*rn
// with Hpos/Hneg = mean of top/bottom 16 of h_n.
// R4: shfl-based intra-wave tournament (no exec-masked LDS tree), ONE barrier.
// ---------------------------------------------------------------------------
__global__ __launch_bounds__(256)
void prep_kernel(const float4* __restrict__ R4,     // f_rad   as float4 [32][256]
                 const float4* __restrict__ H4,     // f_histo as float4 [32][512]
                 const unsigned char* __restrict__ rad_mask,
                 const unsigned char* __restrict__ histo_mask,
                 const float4* __restrict__ bias4,  // [256]
                 const float4* __restrict__ token4, // [256]
                 float4* __restrict__ F4,           // [32][512]
                 float4* __restrict__ out4)         // [32][256]
{
    __shared__ __align__(16) float wlP[4][16];
    __shared__ __align__(16) float wlN[4][16];
    __shared__ float redH[4], redR[4];

    const int b = blockIdx.x;
    const int t = threadIdx.x;
    const int wave = t >> 6, lane = t & 63;

    // ---- loads (issue early) ----
    const float4 h0 = H4[b * 512 + t];
    const float4 h1 = H4[b * 512 + 256 + t];
    const float4 rv4 = R4[b * 256 + t];
    const float4 bv = bias4[t];
    const float4 tv = token4[t];

    // ---- h sum of squares: wave butterfly + LDS combine ----
    float ss = h0.x * h0.x + h0.y * h0.y + h0.z * h0.z + h0.w * h0.w
             + h1.x * h1.x + h1.y * h1.y + h1.z * h1.z + h1.w * h1.w;
#pragma unroll
    for (int off = 1; off < 64; off <<= 1) ss += __shfl_xor(ss, off, 64);
    if (lane == 0) redH[wave] = ss;

    // ---- r sum of squares ----
    float ss2 = rv4.x * rv4.x + rv4.y * rv4.y + rv4.z * rv4.z + rv4.w * rv4.w;
#pragma unroll
    for (int off = 1; off < 64; off <<= 1) ss2 += __shfl_xor(ss2, off, 64);
    if (lane == 0) redR[wave] = ss2;

    // ---- per-thread sorted-8 lists (pos and negated for bottom) ----
    float sp[8] = {h0.x, h0.y, h0.z, h0.w, h1.x, h1.y, h1.z, h1.w};
    float sn[8];
#pragma unroll
    for (int i = 0; i < 8; ++i) sn[i] = -sp[i];
    sort8_desc(sp);
    sort8_desc(sn);

    // ---- intra-wave tournament: 6 shfl levels, every lane keeps top-16 ----
    float vp[16], vn[16];
    {   // level 1: sorted-8 pair -> sorted-16 (exchange 8 values)
        float wp8[8], wn8[8];
#pragma unroll
        for (int i = 0; i < 8; ++i) {
            wp8[i] = __shfl_xor(sp[i], 1, 64);
            wn8[i] = __shfl_xor(sn[i], 1, 64);
        }
        merge8to16(sp, wp8, vp);
        merge8to16(sn, wn8, vn);
    }
#pragma unroll
    for (int off = 2; off <= 32; off <<= 1) {   // levels 2..6
        float wp[16], wn[16];
#pragma unroll
        for (int i = 0; i < 16; ++i) {
            wp[i] = __shfl_xor(vp[i], off, 64);
            wn[i] = __shfl_xor(vn[i], off, 64);
        }
        merge16(vp, wp);
        merge16(vn, wn);
    }

    // ---- publish per-wave lists (all lanes identical; lane 0 writes) ----
    if (lane == 0) {
#pragma unroll
        for (int i = 0; i < 16; ++i) { wlP[wave][i] = vp[i]; wlN[wave][i] = vn[i]; }
    }
    __syncthreads();   // the ONLY barrier: covers redH, redR, wlP, wlN

    // ---- every thread merges the 4 wave lists redundantly ----
    float aP[16], bP[16], cP[16], dP[16];
#pragma unroll
    for (int i = 0; i < 16; ++i) {
        aP[i] = wlP[0][i]; bP[i] = wlP[1][i];
        cP[i] = wlP[2][i]; dP[i] = wlP[3][i];
    }
    merge16(aP, bP); merge16(cP, dP); merge16(aP, cP);
    float aN[16], bN[16], cN[16], dN[16];
#pragma unroll
    for (int i = 0; i < 16; ++i) {
        aN[i] = wlN[0][i]; bN[i] = wlN[1][i];
        cN[i] = wlN[2][i]; dN[i] = wlN[3][i];
    }
    merge16(aN, bN); merge16(cN, dN); merge16(aN, cN);

    float sumP = 0.f, sumN = 0.f;
#pragma unroll
    for (int i = 0; i < 16; ++i) { sumP += aP[i]; sumN += aN[i]; }

    const float hnorm = fmaxf(sqrtf(redH[0] + redH[1] + redH[2] + redH[3]), 1e-12f);
    const float rnorm = fmaxf(sqrtf(redR[0] + redR[1] + redR[2] + redR[3]), 1e-12f);
    const float Hpos = sumP / (16.f * hnorm);    // mean of top-16 of h_n
    const float Hneg = -sumN / (16.f * hnorm);   // mean of bottom-16 of h_n
    const float inv_r = 1.f / rnorm;

    // ---- write F = [pos_map ; neg_map] (float4) ----
    float4 p, q;
    {
        float rn;
        rn = rv4.x * inv_r; p.x = rn * (rn > 0.f ? Hpos : Hneg); q.x = -rn * (rn > 0.f ? Hneg : Hpos);
        rn = rv4.y * inv_r; p.y = rn * (rn > 0.f ? Hpos : Hneg); q.y = -rn * (rn > 0.f ? Hneg : Hpos);
        rn = rv4.z * inv_r; p.z = rn * (rn > 0.f ? Hpos : Hneg); q.z = -rn * (rn > 0.f ? Hneg : Hpos);
        rn = rv4.w * inv_r; p.w = rn * (rn > 0.f ? Hpos : Hneg); q.w = -rn * (rn > 0.f ? Hneg : Hpos);
    }
    F4[b * 512 + t] = p;
    F4[b * 512 + 256 + t] = q;

    // ---- out init: bias + token*flag (gemm atomicAdds on top) ----
    const float flag = (rad_mask[b] != 0 && histo_mask[b] != 0) ? 0.f : 1.f;
    float4 o;
    o.x = bv.x + tv.x * flag;
    o.y = bv.y + tv.y * flag;
    o.z = bv.z + tv.z * flag;
    o.w = bv.w + tv.w * flag;
    out4[b * 256 + t] = o;
}

// ---------------------------------------------------------------------------
// Kernel B: out[b,c] += sum_k F[b,k] * W[c,k]   (UNCHANGED from R3 — near its
// W-streaming floor: grid (128,8) = 4 blocks/CU, 63-shfl transpose reduce.)
// ---------------------------------------------------------------------------
__global__ __launch_bounds__(256, 4)
void gemm_kernel(const float4* __restrict__ F4,
                 const float4* __restrict__ WF4,
                 float* __restrict__ out)
{
    const int t = threadIdx.x;
    const int wave = t >> 6, lane = t & 63;
    const int c0 = blockIdx.x * 8 + wave * 2;
    const int kk4 = blockIdx.y * 64 + lane;      // float4 index in [0,512)

    const float4 w0 = WF4[(size_t)c0 * 512 + kk4];
    const float4 w1 = WF4[(size_t)(c0 + 1) * 512 + kk4];

    float acc0[32], acc1[32];
#pragma unroll
    for (int b = 0; b < 32; ++b) { acc0[b] = 0.f; acc1[b] = 0.f; }

#pragma unroll
    for (int bb = 0; bb < 32; bb += 4) {
        float4 fv[4];
#pragma unroll
        for (int u = 0; u < 4; ++u) fv[u] = F4[(bb + u) * 512 + kk4];
#pragma unroll
        for (int u = 0; u < 4; ++u) {
            const int b = bb + u;
            acc0[b] = fmaf(fv[u].x, w0.x, acc0[b]);
            acc0[b] = fmaf(fv[u].y, w0.y, acc0[b]);
            acc0[b] = fmaf(fv[u].z, w0.z, acc0[b]);
            acc0[b] = fmaf(fv[u].w, w0.w, acc0[b]);
            acc1[b] = fmaf(fv[u].x, w1.x, acc1[b]);
            acc1[b] = fmaf(fv[u].y, w1.y, acc1[b]);
            acc1[b] = fmaf(fv[u].z, w1.z, acc1[b]);
            acc1[b] = fmaf(fv[u].w, w1.w, acc1[b]);
        }
    }

    // ---- c-fold (offset 1): z[b] = k-partial for c = c0+(lane&1) ----
    const bool odd = lane & 1;
    float z[32];
#pragma unroll
    for (int b = 0; b < 32; ++b) {
        float send = odd ? acc0[b] : acc1[b];    // value the partner keeps
        float recv = __shfl_xor(send, 1, 64);
        z[b] = (odd ? acc1[b] : acc0[b]) + recv;
    }

    // ---- register-halving reduce over 32 lane-pairs ----
#pragma unroll
    for (int j = 0; j < 5; ++j) {
        const int o = 2 << j;
        const bool hi = (lane & o) != 0;
        const int n = 32 >> (j + 1);
#pragma unroll
        for (int m = 0; m < n; ++m) {
            float send = hi ? z[2 * m] : z[2 * m + 1];
            float recv = __shfl_xor(send, o, 64);
            z[m] = (hi ? z[2 * m + 1] : z[2 * m]) + recv;
        }
    }

    // lane l holds full k-partial for b = l>>1, c = c0 + (l&1)
    atomicAdd(&out[(lane >> 1) * NC + c0 + (lane & 1)], z[0]);
}

extern "C" void kernel_launch(void* const* d_in, const int* in_sizes, int n_in,
                              void* d_out, int out_size, void* d_ws, size_t ws_size,
                              hipStream_t stream) {
    const float* f_rad       = (const float*)d_in[0];
    const float* f_histo     = (const float*)d_in[1];
    const unsigned char* rm  = (const unsigned char*)d_in[2];
    const unsigned char* hm  = (const unsigned char*)d_in[3];
    const float* W           = (const float*)d_in[4];
    const float* bias        = (const float*)d_in[5];
    const float* token       = (const float*)d_in[6];
    float* out = (float*)d_out;
    float* F   = (float*)d_ws;   // 32*2048 floats = 256 KB

    prep_kernel<<<NB, 256, 0, stream>>>((const float4*)f_rad, (const float4*)f_histo,
                                        rm, hm, (const float4*)bias,
                                        (const float4*)token,
                                        (float4*)F, (float4*)out);
    dim3 grid(128, 8);
    gemm_kernel<<<grid, 256, 0, stream>>>((const float4*)F, (const float4*)W, out);
}